// Round 5
// baseline (809.114 us; speedup 1.0000x reference)
//
#include <hip/hip_runtime.h>

typedef __bf16 bf16;
typedef __bf16 bf16x8 __attribute__((ext_vector_type(8)));
typedef float f32x4 __attribute__((ext_vector_type(4)));

#define AS1(p) ((const __attribute__((address_space(1))) void*)(p))
#define AS3(p) ((__attribute__((address_space(3))) void*)(p))

static __device__ __forceinline__ void nt_store_bf16(bf16 v, bf16* p) {
  short s;
  __builtin_memcpy(&s, &v, 2);
  __builtin_nontemporal_store(s, (short*)p);
}

// ---------------- pack & window-permute x (fp32) -> win (bf16) ----------------
__global__ void k_pack_win(const float* __restrict__ x, bf16* __restrict__ win) {
  int idx = blockIdx.x * 256 + threadIdx.x;  // one thread = 8 elems
  int r = idx / 160;
  int c8 = idx - r * 160;
  int w = r >> 8, n = r & 255;
  int b = w >> 6, hb = (w >> 3) & 7, wb = w & 7;
  int t = n >> 6, i = (n >> 3) & 7, j = n & 7;
  size_t srow = (size_t)((b * 4 + t) * 4096 + (hb * 8 + i) * 64 + wb * 8 + j);
  const float4* s = (const float4*)(x + srow * 1280 + c8 * 8);
  float4 f0 = s[0], f1 = s[1];
  bf16x8 o;
  o[0] = (bf16)f0.x; o[1] = (bf16)f0.y; o[2] = (bf16)f0.z; o[3] = (bf16)f0.w;
  o[4] = (bf16)f1.x; o[5] = (bf16)f1.y; o[6] = (bf16)f1.z; o[7] = (bf16)f1.w;
  *(bf16x8*)(win + (size_t)idx * 8) = o;
}

// ---------------- transpose + convert weights: (K,N) f32 -> (N,K) bf16 ----------------
__global__ void k_transpose_w(const float* __restrict__ w, bf16* __restrict__ wt,
                              int K, int N) {
  __shared__ float tile[32][33];
  int tx = threadIdx.x & 31, ty = threadIdx.x >> 5;
  int c0 = blockIdx.x * 32, r0 = blockIdx.y * 32;
#pragma unroll
  for (int yy = ty; yy < 32; yy += 8)
    tile[yy][tx] = w[(size_t)(r0 + yy) * N + c0 + tx];
  __syncthreads();
#pragma unroll
  for (int yy = ty; yy < 32; yy += 8)
    wt[(size_t)(c0 + yy) * K + r0 + tx] = (bf16)tile[tx][yy];
}

// ---------------- MRoPE cos/sin table: [n=256][c=64] interleaved (cos,sin) ----------------
__global__ void k_rope_table(float* __restrict__ tab) {
  int idx = blockIdx.x * 256 + threadIdx.x;  // 16384
  int n = idx >> 6, c = idx & 63;
  int t = n >> 6, i = (n >> 3) & 7, j = n & 7;
  float pos = (c < 16) ? (float)t : ((c < 40) ? (float)i : (float)j);
  float inv = powf(10000.f, -(float)c * (1.f / 64.f));
  float a = pos * inv;
  tab[idx * 2] = cosf(a);
  tab[idx * 2 + 1] = sinf(a);
}

// ---------------- GEMM: 256x256 tile, BK=64, 8-wave, 4-phase counted-vmcnt ----------------
// C = A(M,1280; stride lda) * Bt(N,1280)^T + bias.  nnb = number of 256-wide n-blocks.
// R5 XCD map: A-reuse-major — resident set per XCD = few A-panels (L2) x all n (B via L3).
// EPI 0: bf16 NT out (stride ldc). EPI 1: f32 NT out with reverse-window row permute.
template <int EPI>
__global__ __launch_bounds__(512, 2) void k_gemm(
    const bf16* __restrict__ A, int lda, const bf16* __restrict__ Bt,
    const float* __restrict__ bias, void* __restrict__ Cout, int ldc, int nnb) {
  __shared__ bf16 sA[2][16384];  // [buf][256 rows][64 k] swizzled
  __shared__ bf16 sB[2][16384];
  const int tid = threadIdx.x, lane = tid & 63, wv = tid >> 6;
  const int wm = wv >> 2, wn = wv & 3;         // 2M x 4N waves, 128x64 per wave
  const int lq = lane >> 4, lr = lane & 15;

  // XCD chunking, n-fastest within each XCD's chunk (A-panel L2 reuse).
  int wg_local = blockIdx.x >> 3;
  int xcd = blockIdx.x & 7;
  int m_blk = (xcd << 4) + wg_local / nnb;
  int n_blk = wg_local % nnb;
  const int m0 = m_blk * 256, n0 = n_blk * 256;

  const bf16* Ab = A + (size_t)m0 * lda;
  const bf16* Bb = Bt + (size_t)n0 * 1280;
  const int srow = tid >> 3;                // 0..63 staging row within 64-row round
  const int skg = (tid & 7) ^ (srow & 7);   // swizzled k-group (involution with read XOR)
  const int sldso = wv * 512;               // per-wave elems within an 8KB round

#define WAIT_LGKM0()                                                            \
  do {                                                                          \
    asm volatile("s_waitcnt lgkmcnt(0)" ::: "memory");                          \
    __builtin_amdgcn_sched_barrier(0);                                          \
  } while (0)

#define WAIT_VM(N)                                                              \
  do {                                                                          \
    asm volatile("s_waitcnt vmcnt(" #N ")" ::: "memory");                       \
    __builtin_amdgcn_sched_barrier(0);                                          \
  } while (0)

#define STAGE_A(bufidx, h, kt)                                                  \
  do {                                                                          \
    __builtin_amdgcn_global_load_lds(                                           \
        AS1(Ab + (size_t)((h)*128 + srow) * lda + (kt)*64 + skg * 8),           \
        AS3(&sA[bufidx][(h)*8192 + sldso]), 16, 0, 0);                          \
    __builtin_amdgcn_global_load_lds(                                           \
        AS1(Ab + (size_t)((h)*128 + 64 + srow) * lda + (kt)*64 + skg * 8),      \
        AS3(&sA[bufidx][(h)*8192 + 4096 + sldso]), 16, 0, 0);                   \
  } while (0)

#define STAGE_B(bufidx, h, kt)                                                  \
  do {                                                                          \
    __builtin_amdgcn_global_load_lds(                                           \
        AS1(Bb + (size_t)((h)*128 + srow) * 1280 + (kt)*64 + skg * 8),          \
        AS3(&sB[bufidx][(h)*8192 + sldso]), 16, 0, 0);                          \
    __builtin_amdgcn_global_load_lds(                                           \
        AS1(Bb + (size_t)((h)*128 + 64 + srow) * 1280 + (kt)*64 + skg * 8),     \
        AS3(&sB[bufidx][(h)*8192 + 4096 + sldso]), 16, 0, 0);                   \
  } while (0)

#define LOAD_A(mh)                                                              \
  _Pragma("unroll") for (int mt = 0; mt < 4; ++mt)                              \
  _Pragma("unroll") for (int kb = 0; kb < 2; ++kb) {                            \
    int row_ = wm * 128 + (mh)*64 + mt * 16 + lr;                               \
    int ksw_ = (kb * 32 + lq * 8) ^ ((lr & 7) << 3);                            \
    af[mt][kb] = *(const bf16x8*)&pA[row_ * 64 + ksw_];                         \
  }

#define LOAD_B(dst, nh)                                                         \
  _Pragma("unroll") for (int nt = 0; nt < 2; ++nt)                              \
  _Pragma("unroll") for (int kb = 0; kb < 2; ++kb) {                            \
    int row_ = wn * 64 + (nh)*32 + nt * 16 + lr;                                \
    int ksw_ = (kb * 32 + lq * 8) ^ ((lr & 7) << 3);                            \
    dst[nt][kb] = *(const bf16x8*)&pB[row_ * 64 + ksw_];                        \
  }

#define MFMA_Q(MH, NH, bvec)                                                    \
  _Pragma("unroll") for (int mt = 0; mt < 4; ++mt)                              \
  _Pragma("unroll") for (int nt = 0; nt < 2; ++nt)                              \
  _Pragma("unroll") for (int kb = 0; kb < 2; ++kb)                              \
    acc[(MH)*4 + mt][(NH)*2 + nt] = __builtin_amdgcn_mfma_f32_16x16x32_bf16(    \
        af[mt][kb], bvec[nt][kb], acc[(MH)*4 + mt][(NH)*2 + nt], 0, 0, 0);

  f32x4 acc[8][4];
#pragma unroll
  for (int i = 0; i < 8; ++i)
#pragma unroll
    for (int j = 0; j < 4; ++j) acc[i][j] = (f32x4){0.f, 0.f, 0.f, 0.f};

  // Prologue: tile0 A+B, tile1 B; keep tile1-B in flight past the wait.
  STAGE_A(0, 0, 0); STAGE_A(0, 1, 0);
  STAGE_B(0, 0, 0); STAGE_B(0, 1, 0);
  STAGE_B(1, 0, 1); STAGE_B(1, 1, 1);
  WAIT_VM(4);
  __builtin_amdgcn_s_barrier();

  bf16x8 af[4][2], bfa[2][2], bfb[2][2];

#pragma unroll 2
  for (int t = 0; t < 20; ++t) {
    const int b = t & 1, bn = b ^ 1;
    const int ktA = (t + 1 < 20) ? t + 1 : 19;  // clamp: keeps vmcnt counts uniform
    const int ktB = (t + 2 < 20) ? t + 2 : 19;
    const bf16* pA = sA[b];
    const bf16* pB = sB[b];
    // phase 0: read A(mh0)+B(nh0); stage A-half0 of tile t+1
    LOAD_A(0);
    LOAD_B(bfa, 0);
    STAGE_A(bn, 0, ktA);
    asm volatile("s_waitcnt lgkmcnt(8)" ::: "memory");  // early-drain hint (12 reads issued)
    __builtin_amdgcn_sched_barrier(0);
    __builtin_amdgcn_s_barrier();
    WAIT_LGKM0();
    __builtin_amdgcn_s_setprio(1);
    MFMA_Q(0, 0, bfa);
    __builtin_amdgcn_s_setprio(0);
    __builtin_amdgcn_sched_barrier(0);
    __builtin_amdgcn_s_barrier();
    // phase 1: read B(nh1); stage A-half1 of tile t+1
    LOAD_B(bfb, 1);
    STAGE_A(bn, 1, ktA);
    __builtin_amdgcn_s_barrier();
    WAIT_LGKM0();
    __builtin_amdgcn_s_setprio(1);
    MFMA_Q(0, 1, bfb);
    __builtin_amdgcn_s_setprio(0);
    __builtin_amdgcn_sched_barrier(0);
    __builtin_amdgcn_s_barrier();
    // phase 2: read A(mh1); stage B-half0 of tile t+2 (region retired after ph1)
    LOAD_A(1);
    STAGE_B(b, 0, ktB);
    __builtin_amdgcn_s_barrier();
    WAIT_LGKM0();
    __builtin_amdgcn_s_setprio(1);
    MFMA_Q(1, 0, bfa);
    __builtin_amdgcn_s_setprio(0);
    __builtin_amdgcn_sched_barrier(0);
    __builtin_amdgcn_s_barrier();
    // phase 3: stage B-half1 of tile t+2; counted vmcnt(4) then tile boundary
    STAGE_B(b, 1, ktB);
    __builtin_amdgcn_s_barrier();
    WAIT_LGKM0();
    __builtin_amdgcn_s_setprio(1);
    MFMA_Q(1, 1, bfb);
    __builtin_amdgcn_s_setprio(0);
    WAIT_VM(4);
    __builtin_amdgcn_s_barrier();
  }

#pragma unroll
  for (int ni = 0; ni < 4; ++ni) {
    int col = n0 + wn * 64 + ni * 16 + lr;
    float bv = bias[col];
#pragma unroll
    for (int mi = 0; mi < 8; ++mi) {
#pragma unroll
      for (int r = 0; r < 4; ++r) {
        int row = m0 + wm * 128 + mi * 16 + lq * 4 + r;
        float v = acc[mi][ni][r] + bv;
        if constexpr (EPI == 0) {
          nt_store_bf16((bf16)v, &((bf16*)Cout)[(size_t)row * ldc + col]);
        } else {
          int w = row >> 8, n = row & 255;
          int b2 = w >> 6, hb = (w >> 3) & 7, wb = w & 7;
          int t2 = n >> 6, i2 = (n >> 3) & 7, j2 = n & 7;
          size_t orow = (size_t)((b2 * 4 + t2) * 4096 + (hb * 8 + i2) * 64 + wb * 8 + j2);
          __builtin_nontemporal_store(v, &((float*)Cout)[orow * ldc + col]);
        }
      }
    }
  }
#undef STAGE_A
#undef STAGE_B
#undef LOAD_A
#undef LOAD_B
#undef MFMA_Q
#undef WAIT_LGKM0
#undef WAIT_VM
}

// ---------------- attention + fused MRoPE: one block per (window, head) ----------------
__global__ __launch_bounds__(512) void k_attn(bf16* __restrict__ qkv,
                                              const float* __restrict__ tab) {
  int wh = blockIdx.x;
  int win = wh / 10, h = wh - win * 10;
  bf16* base = qkv + (size_t)win * 256 * 3840 + h * 128;
  const int tid = threadIdx.x, lane = tid & 63, wv = tid >> 6;
  const int lq = lane >> 4, lr = lane & 15;
  const int qrow0 = wv * 32;

  __shared__ bf16 Kl[64 * 136];    // [tok][d], pad +8
  __shared__ bf16 Vt[128 * 72];    // [d][tok], pad +8
  __shared__ bf16 Pl[8][16 * 72];  // per-wave P strip

  // Q fragments + in-register RoPE + scale
  bf16x8 qf[2][4];
#pragma unroll
  for (int mt = 0; mt < 2; ++mt) {
    int n = qrow0 + mt * 16 + lr;
#pragma unroll
    for (int kq = 0; kq < 4; ++kq)
      qf[mt][kq] = *(const bf16x8*)(base + (size_t)n * 3840 + kq * 32 + lq * 8);
    const float* tb = tab + (n * 64 + lq * 8) * 2;
#pragma unroll
    for (int kq = 0; kq < 2; ++kq)
#pragma unroll
      for (int e = 0; e < 8; ++e) {
        float cs = tb[(kq * 32 + e) * 2], sn = tb[(kq * 32 + e) * 2 + 1];
        float lo = (float)qf[mt][kq][e], hi = (float)qf[mt][kq + 2][e];
        qf[mt][kq][e] = (bf16)((lo * cs - hi * sn) * 0.08838834764831845f);
        qf[mt][kq + 2][e] = (bf16)((hi * cs + lo * sn) * 0.08838834764831845f);
      }
  }

  float mrun[2][4], lrun[2][4];
  f32x4 oacc[2][8];
#pragma unroll
  for (int mt = 0; mt < 2; ++mt)
#pragma unroll
    for (int r = 0; r < 4; ++r) { mrun[mt][r] = -1e30f; lrun[mt][r] = 0.f; }
#pragma unroll
  for (int mt = 0; mt < 2; ++mt)
#pragma unroll
    for (int dt = 0; dt < 8; ++dt) oacc[mt][dt] = (f32x4){0.f, 0.f, 0.f, 0.f};

  for (int kb_t = 0; kb_t < 4; ++kb_t) {
    __syncthreads();
    // stage K block [64][128] with fused RoPE: 512 items (row, col-pair)
    {
      int rr = tid >> 3, cp = tid & 7;
      const bf16* krow = base + 1280 + (size_t)(kb_t * 64 + rr) * 3840;
      bf16x8 klo = *(const bf16x8*)(krow + cp * 8);
      bf16x8 khi = *(const bf16x8*)(krow + cp * 8 + 64);
      const float* tb = tab + ((kb_t * 64 + rr) * 64 + cp * 8) * 2;
      bf16x8 olo, ohi;
#pragma unroll
      for (int e = 0; e < 8; ++e) {
        float cs = tb[e * 2], sn = tb[e * 2 + 1];
        float lo = (float)klo[e], hi = (float)khi[e];
        olo[e] = (bf16)(lo * cs - hi * sn);
        ohi[e] = (bf16)(hi * cs + lo * sn);
      }
      *(bf16x8*)(Kl + rr * 136 + cp * 8) = olo;
      *(bf16x8*)(Kl + rr * 136 + cp * 8 + 64) = ohi;
    }
    // stage V^T block [128][64]
#pragma unroll
    for (int p = 0; p < 2; ++p) {
      int item = p * 512 + tid;
      int rr = item >> 4, cc = item & 15;
      bf16x8 vv = *(const bf16x8*)(base + 2560 + (size_t)(kb_t * 64 + rr) * 3840 + cc * 8);
#pragma unroll
      for (int ee = 0; ee < 8; ++ee) {
        int e = (ee + cc) & 7;
        Vt[(cc * 8 + e) * 72 + rr] = vv[e];
      }
    }
    __syncthreads();

    // S = Q K^T
    f32x4 s[2][4];
#pragma unroll
    for (int mt = 0; mt < 2; ++mt)
#pragma unroll
      for (int nt = 0; nt < 4; ++nt) s[mt][nt] = (f32x4){0.f, 0.f, 0.f, 0.f};
#pragma unroll
    for (int nt = 0; nt < 4; ++nt) {
      bf16x8 kf[4];
#pragma unroll
      for (int kq = 0; kq < 4; ++kq)
        kf[kq] = *(const bf16x8*)(Kl + (nt * 16 + lr) * 136 + kq * 32 + lq * 8);
#pragma unroll
      for (int kq = 0; kq < 4; ++kq) {
        s[0][nt] = __builtin_amdgcn_mfma_f32_16x16x32_bf16(qf[0][kq], kf[kq], s[0][nt], 0, 0, 0);
        s[1][nt] = __builtin_amdgcn_mfma_f32_16x16x32_bf16(qf[1][kq], kf[kq], s[1][nt], 0, 0, 0);
      }
    }

#pragma unroll
    for (int mt = 0; mt < 2; ++mt) {
#pragma unroll
      for (int r = 0; r < 4; ++r) {
        float mx = fmaxf(fmaxf(s[mt][0][r], s[mt][1][r]), fmaxf(s[mt][2][r], s[mt][3][r]));
        mx = fmaxf(mx, __shfl_xor(mx, 1));
        mx = fmaxf(mx, __shfl_xor(mx, 2));
        mx = fmaxf(mx, __shfl_xor(mx, 4));
        mx = fmaxf(mx, __shfl_xor(mx, 8));
        float mold = mrun[mt][r];
        float mnew = fmaxf(mold, mx);
        float corr = __expf(mold - mnew);
        mrun[mt][r] = mnew;
        float rs = 0.f;
#pragma unroll
        for (int nt = 0; nt < 4; ++nt) {
          float p = __expf(s[mt][nt][r] - mnew);
          s[mt][nt][r] = p;
          rs += p;
        }
        rs += __shfl_xor(rs, 1);
        rs += __shfl_xor(rs, 2);
        rs += __shfl_xor(rs, 4);
        rs += __shfl_xor(rs, 8);
        lrun[mt][r] = lrun[mt][r] * corr + rs;
#pragma unroll
        for (int dt = 0; dt < 8; ++dt) oacc[mt][dt][r] *= corr;
#pragma unroll
        for (int nt = 0; nt < 4; ++nt)
          Pl[wv][(lq * 4 + r) * 72 + nt * 16 + lr] = (bf16)s[mt][nt][r];
      }
      asm volatile("s_waitcnt lgkmcnt(0)" ::: "memory");
      __builtin_amdgcn_sched_barrier(0);
#pragma unroll
      for (int kq = 0; kq < 2; ++kq) {
        bf16x8 pf = *(const bf16x8*)(Pl[wv] + lr * 72 + kq * 32 + lq * 8);
#pragma unroll
        for (int dt = 0; dt < 8; ++dt) {
          bf16x8 vf = *(const bf16x8*)(Vt + (dt * 16 + lr) * 72 + kq * 32 + lq * 8);
          oacc[mt][dt] = __builtin_amdgcn_mfma_f32_16x16x32_bf16(pf, vf, oacc[mt][dt], 0, 0, 0);
        }
      }
    }
  }

#pragma unroll
  for (int mt = 0; mt < 2; ++mt) {
#pragma unroll
    for (int r = 0; r < 4; ++r) {
      float inv = 1.f / lrun[mt][r];
#pragma unroll
      for (int dt = 0; dt < 8; ++dt) {
        int trow = qrow0 + mt * 16 + lq * 4 + r;
        base[(size_t)trow * 3840 + dt * 16 + lr] = (bf16)(oacc[mt][dt][r] * inv);
      }
    }
  }
}

extern "C" void kernel_launch(void* const* d_in, const int* in_sizes, int n_in,
                              void* d_out, int out_size, void* d_ws, size_t ws_size,
                              hipStream_t stream) {
  const float* x      = (const float*)d_in[0];
  const float* w_qkv  = (const float*)d_in[1];
  const float* b_qkv  = (const float*)d_in[2];
  const float* w_proj = (const float*)d_in[3];
  const float* b_proj = (const float*)d_in[4];

  // Transients in d_out (dead before final GEMM rewrites it):
  char* outc = (char*)d_out;
  bf16* win   = (bf16*)outc;                          // 32768x1280 bf16
  bf16* wqkvT = (bf16*)(outc + 83886080);             // 3840x1280 bf16
  float* tab  = (float*)(outc + 83886080 + 9830400);  // 256x64x2 f32
  // Workspace:
  char* wsc = (char*)d_ws;
  bf16* qkv    = (bf16*)wsc;                          // 32768x3840 bf16
  bf16* wprojT = (bf16*)(wsc + 251658240);            // 1280x1280 bf16

  k_pack_win<<<20480, 256, 0, stream>>>(x, win);
  k_transpose_w<<<dim3(120, 40), 256, 0, stream>>>(w_qkv, wqkvT, 1280, 3840);
  k_transpose_w<<<dim3(40, 40), 256, 0, stream>>>(w_proj, wprojT, 1280, 1280);
  k_rope_table<<<64, 256, 0, stream>>>(tab);
  k_gemm<0><<<1920, 512, 0, stream>>>(win, 1280, wqkvT, b_qkv, (void*)qkv, 3840, 15);
  k_attn<<<1280, 512, 0, stream>>>(qkv, tab);  // fused RoPE; writes O over q-section
  k_gemm<1><<<640, 512, 0, stream>>>(qkv, 3840, wprojT, b_proj, d_out, 1280, 5);
}

// Round 6
// 712.904 us; speedup vs baseline: 1.1350x; 1.1350x over previous
//
#include <hip/hip_runtime.h>

typedef __bf16 bf16;
typedef __bf16 bf16x8 __attribute__((ext_vector_type(8)));
typedef float f32x4 __attribute__((ext_vector_type(4)));

#define AS1(p) ((const __attribute__((address_space(1))) void*)(p))
#define AS3(p) ((__attribute__((address_space(3))) void*)(p))

template <int IMM>
static __device__ __forceinline__ bf16x8 dsread(unsigned a) {
  bf16x8 d;
  asm volatile("ds_read_b128 %0, %1 offset:%2" : "=v"(d) : "v"(a), "i"(IMM) : "memory");
  return d;
}

// ---------------- pack & window-permute x (fp32) -> win (bf16) ----------------
__global__ void k_pack_win(const float* __restrict__ x, bf16* __restrict__ win) {
  int idx = blockIdx.x * 256 + threadIdx.x;  // one thread = 8 elems
  int r = idx / 160;
  int c8 = idx - r * 160;
  int w = r >> 8, n = r & 255;
  int b = w >> 6, hb = (w >> 3) & 7, wb = w & 7;
  int t = n >> 6, i = (n >> 3) & 7, j = n & 7;
  size_t srow = (size_t)((b * 4 + t) * 4096 + (hb * 8 + i) * 64 + wb * 8 + j);
  const float4* s = (const float4*)(x + srow * 1280 + c8 * 8);
  float4 f0 = s[0], f1 = s[1];
  bf16x8 o;
  o[0] = (bf16)f0.x; o[1] = (bf16)f0.y; o[2] = (bf16)f0.z; o[3] = (bf16)f0.w;
  o[4] = (bf16)f1.x; o[5] = (bf16)f1.y; o[6] = (bf16)f1.z; o[7] = (bf16)f1.w;
  *(bf16x8*)(win + (size_t)idx * 8) = o;
}

// ---------------- transpose + convert weights: (K,N) f32 -> (N,K) bf16 ----------------
__global__ void k_transpose_w(const float* __restrict__ w, bf16* __restrict__ wt,
                              int K, int N) {
  __shared__ float tile[32][33];
  int tx = threadIdx.x & 31, ty = threadIdx.x >> 5;
  int c0 = blockIdx.x * 32, r0 = blockIdx.y * 32;
#pragma unroll
  for (int yy = ty; yy < 32; yy += 8)
    tile[yy][tx] = w[(size_t)(r0 + yy) * N + c0 + tx];
  __syncthreads();
#pragma unroll
  for (int yy = ty; yy < 32; yy += 8)
    wt[(size_t)(c0 + yy) * K + r0 + tx] = (bf16)tile[tx][yy];
}

// ---------------- MRoPE cos/sin table: [n=256][c=64] interleaved (cos,sin) ----------------
__global__ void k_rope_table(float* __restrict__ tab) {
  int idx = blockIdx.x * 256 + threadIdx.x;  // 16384
  int n = idx >> 6, c = idx & 63;
  int t = n >> 6, i = (n >> 3) & 7, j = n & 7;
  float pos = (c < 16) ? (float)t : ((c < 40) ? (float)i : (float)j);
  float inv = powf(10000.f, -(float)c * (1.f / 64.f));
  float a = pos * inv;
  tab[idx * 2] = cosf(a);
  tab[idx * 2 + 1] = sinf(a);
}

// ---------------- GEMM: 256x256 tile, BK=64, 8-wave, 4-phase counted-vmcnt ----------------
// R6: all LDS read addresses precomputed into VGPRs; buffer/half via asm offset: imm.
// C = A(M,1280; stride lda) * Bt(N,1280)^T + bias.
// EPI 0: bf16 out (stride ldc). EPI 1: f32 out with reverse-window row permute.
template <int EPI>
__global__ __launch_bounds__(512, 2) void k_gemm(
    const bf16* __restrict__ A, int lda, const bf16* __restrict__ Bt,
    const float* __restrict__ bias, void* __restrict__ Cout, int ldc) {
  __shared__ bf16 sAB[4][16384];  // [A buf0 | A buf1 | B buf0 | B buf1], swizzled
  const int tid = threadIdx.x, lane = tid & 63, wv = tid >> 6;
  const int wm = wv >> 2, wn = wv & 3;  // 2M x 4N waves, 128x64 per wave
  const int lq = lane >> 4, lr = lane & 15;

  // XCD map (R3): block i -> XCD i%8; m fast within XCD, n outer.
  int wg_local = blockIdx.x >> 3;
  int xcd = blockIdx.x & 7;
  int n_blk = wg_local >> 4;
  int m_blk = (xcd << 4) + (wg_local & 15);
  const int m0 = m_blk * 256, n0 = n_blk * 256;

  const bf16* Ab = A + (size_t)m0 * lda;
  const bf16* Bb = Bt + (size_t)n0 * 1280;
  const int srow = tid >> 3;               // 0..63 staging row within 64-row round
  const int skg = (tid & 7) ^ (srow & 7);  // swizzled k-group (involution with read XOR)
  const int sldso = wv * 512;              // per-wave elems within an 8KB round

  // ---- precomputed per-lane LDS read addresses (bytes) ----
  const unsigned sbase = (unsigned)(size_t)AS3(&sAB[0][0]);
  const unsigned csw0 = 2u * ((lq * 8) ^ ((lr & 7) << 3));         // kb=0 col bytes
  const unsigned csw1 = 2u * ((32 + lq * 8) ^ ((lr & 7) << 3));    // kb=1
  unsigned aA[4][2], aB[2][2];
#pragma unroll
  for (int mt = 0; mt < 4; ++mt) {
    unsigned rb = sbase + (unsigned)(wm * 128 + mt * 16 + lr) * 128;
    aA[mt][0] = rb + csw0;
    aA[mt][1] = rb + csw1;
  }
#pragma unroll
  for (int nt = 0; nt < 2; ++nt) {
    unsigned rb = sbase + 65536u + (unsigned)(wn * 64 + nt * 16 + lr) * 128;
    aB[nt][0] = rb + csw0;
    aB[nt][1] = rb + csw1;
  }

  // ---- fixed per-lane staging source pointers (kt=0) ----
  const bf16* gA0 = Ab + (size_t)srow * lda + skg * 8;  // rows srow+{0,64,128,192}
  const bf16* gA1 = gA0 + (size_t)64 * lda;
  const bf16* gA2 = gA0 + (size_t)128 * lda;
  const bf16* gA3 = gA0 + (size_t)192 * lda;
  const bf16* gB0 = Bb + (size_t)srow * 1280 + skg * 8;
  const bf16* gB1 = gB0 + (size_t)64 * 1280;
  const bf16* gB2 = gB0 + (size_t)128 * 1280;
  const bf16* gB3 = gB0 + (size_t)192 * 1280;

#define DSTA(b, h, half) (&sAB[(b)][(h)*8192 + (half)*4096 + sldso])
#define DSTB(b, h, half) (&sAB[2 + (b)][(h)*8192 + (half)*4096 + sldso])
#define GLD(src, dst) __builtin_amdgcn_global_load_lds(AS1(src), AS3(dst), 16, 0, 0)

#define WAIT_LGKM0()                                                    \
  do {                                                                  \
    asm volatile("s_waitcnt lgkmcnt(0)" ::: "memory");                  \
    __builtin_amdgcn_sched_barrier(0);                                  \
  } while (0)
#define WAIT_VM4()                                                      \
  do {                                                                  \
    asm volatile("s_waitcnt vmcnt(4)" ::: "memory");                    \
    __builtin_amdgcn_sched_barrier(0);                                  \
  } while (0)

#define RD_A(BUF, MH)                                                   \
  do {                                                                  \
    af[0][0] = dsread<(BUF)*32768 + (MH)*8192>(aA[0][0]);               \
    af[0][1] = dsread<(BUF)*32768 + (MH)*8192>(aA[0][1]);               \
    af[1][0] = dsread<(BUF)*32768 + (MH)*8192>(aA[1][0]);               \
    af[1][1] = dsread<(BUF)*32768 + (MH)*8192>(aA[1][1]);               \
    af[2][0] = dsread<(BUF)*32768 + (MH)*8192>(aA[2][0]);               \
    af[2][1] = dsread<(BUF)*32768 + (MH)*8192>(aA[2][1]);               \
    af[3][0] = dsread<(BUF)*32768 + (MH)*8192>(aA[3][0]);               \
    af[3][1] = dsread<(BUF)*32768 + (MH)*8192>(aA[3][1]);               \
  } while (0)

#define RD_B(dst, BUF, NH)                                              \
  do {                                                                  \
    dst[0][0] = dsread<(BUF)*32768 + (NH)*4096>(aB[0][0]);              \
    dst[0][1] = dsread<(BUF)*32768 + (NH)*4096>(aB[0][1]);              \
    dst[1][0] = dsread<(BUF)*32768 + (NH)*4096>(aB[1][0]);              \
    dst[1][1] = dsread<(BUF)*32768 + (NH)*4096>(aB[1][1]);              \
  } while (0)

#define MFMA_Q(MH, NH, bvec)                                                 \
  _Pragma("unroll") for (int mt = 0; mt < 4; ++mt)                           \
  _Pragma("unroll") for (int nt = 0; nt < 2; ++nt)                           \
  _Pragma("unroll") for (int kb = 0; kb < 2; ++kb)                           \
    acc[(MH)*4 + mt][(NH)*2 + nt] = __builtin_amdgcn_mfma_f32_16x16x32_bf16( \
        af[mt][kb], bvec[nt][kb], acc[(MH)*4 + mt][(NH)*2 + nt], 0, 0, 0);

#define TILE(BUF, T)                                                          \
  do {                                                                        \
    const int kAo = (((T) + 1 < 20) ? ((T) + 1) : 19) * 64;                   \
    const int kBo = (((T) + 2 < 20) ? ((T) + 2) : 19) * 64;                   \
    /* phase 0: read A(mh0)+B(nh0); stage A(t+1) h0 */                        \
    RD_A(BUF, 0);                                                             \
    RD_B(bfa, BUF, 0);                                                        \
    GLD(gA0 + kAo, DSTA(1 - (BUF), 0, 0));                                    \
    GLD(gA1 + kAo, DSTA(1 - (BUF), 0, 1));                                    \
    asm volatile("s_waitcnt lgkmcnt(8)" ::: "memory");                        \
    __builtin_amdgcn_sched_barrier(0);                                        \
    __builtin_amdgcn_s_barrier();                                             \
    WAIT_LGKM0();                                                             \
    __builtin_amdgcn_s_setprio(1);                                            \
    MFMA_Q(0, 0, bfa);                                                        \
    __builtin_amdgcn_s_setprio(0);                                            \
    __builtin_amdgcn_sched_barrier(0);                                        \
    __builtin_amdgcn_s_barrier();                                             \
    /* phase 1: read B(nh1); stage A(t+1) h1 */                               \
    RD_B(bfb, BUF, 1);                                                        \
    GLD(gA2 + kAo, DSTA(1 - (BUF), 1, 0));                                    \
    GLD(gA3 + kAo, DSTA(1 - (BUF), 1, 1));                                    \
    __builtin_amdgcn_s_barrier();                                             \
    WAIT_LGKM0();                                                             \
    __builtin_amdgcn_s_setprio(1);                                            \
    MFMA_Q(0, 1, bfb);                                                        \
    __builtin_amdgcn_s_setprio(0);                                            \
    __builtin_amdgcn_sched_barrier(0);                                        \
    __builtin_amdgcn_s_barrier();                                             \
    /* phase 2: read A(mh1); stage B(t+2) h0 */                               \
    RD_A(BUF, 1);                                                             \
    GLD(gB0 + kBo, DSTB(BUF, 0, 0));                                          \
    GLD(gB1 + kBo, DSTB(BUF, 0, 1));                                          \
    __builtin_amdgcn_s_barrier();                                             \
    WAIT_LGKM0();                                                             \
    __builtin_amdgcn_s_setprio(1);                                            \
    MFMA_Q(1, 0, bfa);                                                        \
    __builtin_amdgcn_s_setprio(0);                                            \
    __builtin_amdgcn_sched_barrier(0);                                        \
    __builtin_amdgcn_s_barrier();                                             \
    /* phase 3: stage B(t+2) h1; counted vmcnt then tile boundary */          \
    GLD(gB2 + kBo, DSTB(BUF, 1, 0));                                          \
    GLD(gB3 + kBo, DSTB(BUF, 1, 1));                                          \
    __builtin_amdgcn_s_barrier();                                             \
    WAIT_LGKM0();                                                             \
    __builtin_amdgcn_s_setprio(1);                                            \
    MFMA_Q(1, 1, bfb);                                                        \
    __builtin_amdgcn_s_setprio(0);                                            \
    WAIT_VM4();                                                               \
    __builtin_amdgcn_s_barrier();                                             \
  } while (0)

  f32x4 acc[8][4];
#pragma unroll
  for (int i = 0; i < 8; ++i)
#pragma unroll
    for (int j = 0; j < 4; ++j) acc[i][j] = (f32x4){0.f, 0.f, 0.f, 0.f};

  // Prologue: A(0)->buf0, B(0)->buf0, B(1)->buf1; keep B(1) in flight.
  GLD(gA0, DSTA(0, 0, 0)); GLD(gA1, DSTA(0, 0, 1));
  GLD(gA2, DSTA(0, 1, 0)); GLD(gA3, DSTA(0, 1, 1));
  GLD(gB0, DSTB(0, 0, 0)); GLD(gB1, DSTB(0, 0, 1));
  GLD(gB2, DSTB(0, 1, 0)); GLD(gB3, DSTB(0, 1, 1));
  GLD(gB0 + 64, DSTB(1, 0, 0)); GLD(gB1 + 64, DSTB(1, 0, 1));
  GLD(gB2 + 64, DSTB(1, 1, 0)); GLD(gB3 + 64, DSTB(1, 1, 1));
  WAIT_VM4();
  __builtin_amdgcn_s_barrier();

  bf16x8 af[4][2], bfa[2][2], bfb[2][2];

  for (int it = 0; it < 10; ++it) {
    TILE(0, 2 * it);
    TILE(1, 2 * it + 1);
  }

#pragma unroll
  for (int ni = 0; ni < 4; ++ni) {
    int col = n0 + wn * 64 + ni * 16 + lr;
    float bv = bias[col];
#pragma unroll
    for (int mi = 0; mi < 8; ++mi) {
#pragma unroll
      for (int r = 0; r < 4; ++r) {
        int row = m0 + wm * 128 + mi * 16 + lq * 4 + r;
        float v = acc[mi][ni][r] + bv;
        if constexpr (EPI == 0) {
          ((bf16*)Cout)[(size_t)row * ldc + col] = (bf16)v;
        } else {
          int w = row >> 8, n = row & 255;
          int b2 = w >> 6, hb = (w >> 3) & 7, wb = w & 7;
          int t2 = n >> 6, i2 = (n >> 3) & 7, j2 = n & 7;
          size_t orow = (size_t)((b2 * 4 + t2) * 4096 + (hb * 8 + i2) * 64 + wb * 8 + j2);
          ((float*)Cout)[orow * ldc + col] = v;
        }
      }
    }
  }
#undef DSTA
#undef DSTB
#undef GLD
#undef WAIT_LGKM0
#undef WAIT_VM4
#undef RD_A
#undef RD_B
#undef MFMA_Q
#undef TILE
}

// ---------------- attention + fused MRoPE: one block per (window, head) ----------------
__global__ __launch_bounds__(512) void k_attn(bf16* __restrict__ qkv,
                                              const float* __restrict__ tab) {
  int wh = blockIdx.x;
  int win = wh / 10, h = wh - win * 10;
  bf16* base = qkv + (size_t)win * 256 * 3840 + h * 128;
  const int tid = threadIdx.x, lane = tid & 63, wv = tid >> 6;
  const int lq = lane >> 4, lr = lane & 15;
  const int qrow0 = wv * 32;

  __shared__ bf16 Kl[64 * 136];    // [tok][d], pad +8
  __shared__ bf16 Vt[128 * 72];    // [d][tok], pad +8
  __shared__ bf16 Pl[8][16 * 72];  // per-wave P strip

  // Q fragments + in-register RoPE + scale
  bf16x8 qf[2][4];
#pragma unroll
  for (int mt = 0; mt < 2; ++mt) {
    int n = qrow0 + mt * 16 + lr;
#pragma unroll
    for (int kq = 0; kq < 4; ++kq)
      qf[mt][kq] = *(const bf16x8*)(base + (size_t)n * 3840 + kq * 32 + lq * 8);
    const float* tb = tab + (n * 64 + lq * 8) * 2;
#pragma unroll
    for (int kq = 0; kq < 2; ++kq)
#pragma unroll
      for (int e = 0; e < 8; ++e) {
        float cs = tb[(kq * 32 + e) * 2], sn = tb[(kq * 32 + e) * 2 + 1];
        float lo = (float)qf[mt][kq][e], hi = (float)qf[mt][kq + 2][e];
        qf[mt][kq][e] = (bf16)((lo * cs - hi * sn) * 0.08838834764831845f);
        qf[mt][kq + 2][e] = (bf16)((hi * cs + lo * sn) * 0.08838834764831845f);
      }
  }

  float mrun[2][4], lrun[2][4];
  f32x4 oacc[2][8];
#pragma unroll
  for (int mt = 0; mt < 2; ++mt)
#pragma unroll
    for (int r = 0; r < 4; ++r) { mrun[mt][r] = -1e30f; lrun[mt][r] = 0.f; }
#pragma unroll
  for (int mt = 0; mt < 2; ++mt)
#pragma unroll
    for (int dt = 0; dt < 8; ++dt) oacc[mt][dt] = (f32x4){0.f, 0.f, 0.f, 0.f};

  for (int kb_t = 0; kb_t < 4; ++kb_t) {
    __syncthreads();
    // stage K block [64][128] with fused RoPE: 512 items (row, col-pair)
    {
      int rr = tid >> 3, cp = tid & 7;
      const bf16* krow = base + 1280 + (size_t)(kb_t * 64 + rr) * 3840;
      bf16x8 klo = *(const bf16x8*)(krow + cp * 8);
      bf16x8 khi = *(const bf16x8*)(krow + cp * 8 + 64);
      const float* tb = tab + ((kb_t * 64 + rr) * 64 + cp * 8) * 2;
      bf16x8 olo, ohi;
#pragma unroll
      for (int e = 0; e < 8; ++e) {
        float cs = tb[e * 2], sn = tb[e * 2 + 1];
        float lo = (float)klo[e], hi = (float)khi[e];
        olo[e] = (bf16)(lo * cs - hi * sn);
        ohi[e] = (bf16)(hi * cs + lo * sn);
      }
      *(bf16x8*)(Kl + rr * 136 + cp * 8) = olo;
      *(bf16x8*)(Kl + rr * 136 + cp * 8 + 64) = ohi;
    }
    // stage V^T block [128][64]
#pragma unroll
    for (int p = 0; p < 2; ++p) {
      int item = p * 512 + tid;
      int rr = item >> 4, cc = item & 15;
      bf16x8 vv = *(const bf16x8*)(base + 2560 + (size_t)(kb_t * 64 + rr) * 3840 + cc * 8);
#pragma unroll
      for (int ee = 0; ee < 8; ++ee) {
        int e = (ee + cc) & 7;
        Vt[(cc * 8 + e) * 72 + rr] = vv[e];
      }
    }
    __syncthreads();

    // S = Q K^T
    f32x4 s[2][4];
#pragma unroll
    for (int mt = 0; mt < 2; ++mt)
#pragma unroll
      for (int nt = 0; nt < 4; ++nt) s[mt][nt] = (f32x4){0.f, 0.f, 0.f, 0.f};
#pragma unroll
    for (int nt = 0; nt < 4; ++nt) {
      bf16x8 kf[4];
#pragma unroll
      for (int kq = 0; kq < 4; ++kq)
        kf[kq] = *(const bf16x8*)(Kl + (nt * 16 + lr) * 136 + kq * 32 + lq * 8);
#pragma unroll
      for (int kq = 0; kq < 4; ++kq) {
        s[0][nt] = __builtin_amdgcn_mfma_f32_16x16x32_bf16(qf[0][kq], kf[kq], s[0][nt], 0, 0, 0);
        s[1][nt] = __builtin_amdgcn_mfma_f32_16x16x32_bf16(qf[1][kq], kf[kq], s[1][nt], 0, 0, 0);
      }
    }

#pragma unroll
    for (int mt = 0; mt < 2; ++mt) {
#pragma unroll
      for (int r = 0; r < 4; ++r) {
        float mx = fmaxf(fmaxf(s[mt][0][r], s[mt][1][r]), fmaxf(s[mt][2][r], s[mt][3][r]));
        mx = fmaxf(mx, __shfl_xor(mx, 1));
        mx = fmaxf(mx, __shfl_xor(mx, 2));
        mx = fmaxf(mx, __shfl_xor(mx, 4));
        mx = fmaxf(mx, __shfl_xor(mx, 8));
        float mold = mrun[mt][r];
        float mnew = fmaxf(mold, mx);
        float corr = __expf(mold - mnew);
        mrun[mt][r] = mnew;
        float rs = 0.f;
#pragma unroll
        for (int nt = 0; nt < 4; ++nt) {
          float p = __expf(s[mt][nt][r] - mnew);
          s[mt][nt][r] = p;
          rs += p;
        }
        rs += __shfl_xor(rs, 1);
        rs += __shfl_xor(rs, 2);
        rs += __shfl_xor(rs, 4);
        rs += __shfl_xor(rs, 8);
        lrun[mt][r] = lrun[mt][r] * corr + rs;
#pragma unroll
        for (int dt = 0; dt < 8; ++dt) oacc[mt][dt][r] *= corr;
#pragma unroll
        for (int nt = 0; nt < 4; ++nt)
          Pl[wv][(lq * 4 + r) * 72 + nt * 16 + lr] = (bf16)s[mt][nt][r];
      }
      asm volatile("s_waitcnt lgkmcnt(0)" ::: "memory");
      __builtin_amdgcn_sched_barrier(0);
#pragma unroll
      for (int kq = 0; kq < 2; ++kq) {
        bf16x8 pf = *(const bf16x8*)(Pl[wv] + lr * 72 + kq * 32 + lq * 8);
#pragma unroll
        for (int dt = 0; dt < 8; ++dt) {
          bf16x8 vf = *(const bf16x8*)(Vt + (dt * 16 + lr) * 72 + kq * 32 + lq * 8);
          oacc[mt][dt] = __builtin_amdgcn_mfma_f32_16x16x32_bf16(pf, vf, oacc[mt][dt], 0, 0, 0);
        }
      }
    }
  }

#pragma unroll
  for (int mt = 0; mt < 2; ++mt) {
#pragma unroll
    for (int r = 0; r < 4; ++r) {
      float inv = 1.f / lrun[mt][r];
#pragma unroll
      for (int dt = 0; dt < 8; ++dt) {
        int trow = qrow0 + mt * 16 + lq * 4 + r;
        base[(size_t)trow * 3840 + dt * 16 + lr] = (bf16)(oacc[mt][dt][r] * inv);
      }
    }
  }
}

extern "C" void kernel_launch(void* const* d_in, const int* in_sizes, int n_in,
                              void* d_out, int out_size, void* d_ws, size_t ws_size,
                              hipStream_t stream) {
  const float* x      = (const float*)d_in[0];
  const float* w_qkv  = (const float*)d_in[1];
  const float* b_qkv  = (const float*)d_in[2];
  const float* w_proj = (const float*)d_in[3];
  const float* b_proj = (const float*)d_in[4];

  // Transients in d_out (dead before final GEMM rewrites it):
  char* outc = (char*)d_out;
  bf16* win   = (bf16*)outc;                          // 32768x1280 bf16
  bf16* wqkvT = (bf16*)(outc + 83886080);             // 3840x1280 bf16
  float* tab  = (float*)(outc + 83886080 + 9830400);  // 256x64x2 f32
  // Workspace:
  char* wsc = (char*)d_ws;
  bf16* qkv    = (bf16*)wsc;                          // 32768x3840 bf16
  bf16* wprojT = (bf16*)(wsc + 251658240);            // 1280x1280 bf16

  k_pack_win<<<20480, 256, 0, stream>>>(x, win);
  k_transpose_w<<<dim3(120, 40), 256, 0, stream>>>(w_qkv, wqkvT, 1280, 3840);
  k_transpose_w<<<dim3(40, 40), 256, 0, stream>>>(w_proj, wprojT, 1280, 1280);
  k_rope_table<<<64, 256, 0, stream>>>(tab);
  k_gemm<0><<<1920, 512, 0, stream>>>(win, 1280, wqkvT, b_qkv, (void*)qkv, 3840);
  k_attn<<<1280, 512, 0, stream>>>(qkv, tab);  // fused RoPE; writes O over q-section
  k_gemm<1><<<640, 512, 0, stream>>>(qkv, 3840, wprojT, b_proj, d_out, 1280);
}